// Round 10
// baseline (384.501 us; speedup 1.0000x reference)
//
#include <hip/hip_runtime.h>
#include <hip/hip_fp16.h>
#include <math.h>

#define N_NODES 50000
#define E_EDGES 800000
#define NCHUNKS ((N_NODES + 1023) / 1024)

typedef _Float16 half8 __attribute__((ext_vector_type(8)));
typedef float f32x4 __attribute__((ext_vector_type(4)));

// ================= CSR build =================
__global__ __launch_bounds__(256) void zero2_kernel(int* a, int* b, int n) {
    int t = blockIdx.x * 256 + threadIdx.x;
    if (t < n) { a[t] = 0; b[t] = 0; }
}

// both atomics in one thread (R9 probe: 1-atomic/thread 2D split REGRESSED 67->78;
// 2 independent atomics per thread gives better memory-side atomic MLP)
__global__ __launch_bounds__(256) void count_rank_kernel(const int* __restrict__ ei0,
                                                         const int* __restrict__ ei1,
                                                         int* cnt_fwd, int* cnt_bwd,
                                                         int* rank_fwd, int* rank_bwd, int e) {
    int t = blockIdx.x * 256 + threadIdx.x;
    if (t < e) {
        rank_fwd[t] = atomicAdd(&cnt_fwd[ei1[t]], 1);   // indeg, rank within dst list
        rank_bwd[t] = atomicAdd(&cnt_bwd[ei0[t]], 1);   // outdeg, rank within src list
    }
}

// ---- grid-parallel exclusive scan, both directions via blockIdx.y ----
__global__ __launch_bounds__(1024) void scan_chunk2_kernel(const int* __restrict__ cnt_f,
                                                           const int* __restrict__ cnt_b,
                                                           int* __restrict__ offs_f,
                                                           int* __restrict__ offs_b,
                                                           int* __restrict__ part_f,
                                                           int* __restrict__ part_b, int n) {
    const int* cnt = blockIdx.y ? cnt_b : cnt_f;
    int* offs = blockIdx.y ? offs_b : offs_f;
    int* partials = blockIdx.y ? part_b : part_f;
    __shared__ int sh[1024];
    int tid = threadIdx.x;
    int i = blockIdx.x * 1024 + tid;
    int v = (i < n) ? cnt[i] : 0;
    sh[tid] = v;
    __syncthreads();
    for (int off = 1; off < 1024; off <<= 1) {
        int add = (tid >= off) ? sh[tid - off] : 0;
        __syncthreads();
        sh[tid] += add;
        __syncthreads();
    }
    if (i < n) offs[i] = sh[tid] - v;
    if (tid == 1023) partials[blockIdx.x] = sh[tid];
}

__global__ __launch_bounds__(64) void scan_partials2_kernel(int* part_f, int* part_b, int nchunks) {
    int* p = blockIdx.x ? part_b : part_f;
    __shared__ int sh[64];
    int tid = threadIdx.x;
    int v = (tid < nchunks) ? p[tid] : 0;
    sh[tid] = v;
    __syncthreads();
    for (int off = 1; off < 64; off <<= 1) {
        int add = (tid >= off) ? sh[tid - off] : 0;
        __syncthreads();
        sh[tid] += add;
        __syncthreads();
    }
    if (tid < nchunks) p[tid] = sh[tid] - v;
    if (tid == 63) p[nchunks] = sh[63];
}

__global__ __launch_bounds__(256) void addback_deg_kernel(int* __restrict__ offs_f,
                                                          int* __restrict__ offs_b,
                                                          const int* __restrict__ part_f,
                                                          const int* __restrict__ part_b,
                                                          const int* __restrict__ cnt_f,
                                                          const int* __restrict__ cnt_b,
                                                          float* dsi, float* dti,
                                                          int n, int nchunks) {
    int i = blockIdx.x * 256 + threadIdx.x;
    if (blockIdx.y == 0) {
        if (i < n) {
            offs_f[i] += part_f[i >> 10];
            dti[i] = rsqrtf((float)(cnt_f[i] + 1));
        } else if (i == n) offs_f[n] = part_f[nchunks];
    } else {
        if (i < n) {
            offs_b[i] += part_b[i >> 10];
            dsi[i] = rsqrtf((float)(cnt_b[i] + 1));
        } else if (i == n) offs_b[n] = part_b[nchunks];
    }
}

__global__ __launch_bounds__(256) void fill2_kernel(const int* __restrict__ ei0,
                                                    const int* __restrict__ ei1,
                                                    const int* __restrict__ rank_f,
                                                    const int* __restrict__ rank_b,
                                                    const int* __restrict__ offs_f,
                                                    const int* __restrict__ offs_b,
                                                    unsigned short* __restrict__ pay_f,
                                                    unsigned short* __restrict__ pay_b, int e) {
    int t = blockIdx.x * 256 + threadIdx.x;
    if (t >= e) return;
    if (blockIdx.y == 0)
        pay_f[offs_f[ei1[t]] + rank_f[t]] = (unsigned short)ei0[t];
    else
        pay_b[offs_b[ei0[t]] + rank_b[t]] = (unsigned short)ei1[t];
}

// ======= conv1 dual linear via MFMA (fp16 in-reg), s/t via blockIdx.y =======
__global__ __launch_bounds__(256) void lin1_mfma_kernel(const float* __restrict__ Xs,
                                                        const float* __restrict__ Xt,
                                                        const float* __restrict__ sWa,
                                                        const float* __restrict__ sba,
                                                        const float* __restrict__ sWb,
                                                        const float* __restrict__ sbb,
                                                        const float* __restrict__ tWa,
                                                        const float* __restrict__ tba,
                                                        const float* __restrict__ tWb,
                                                        const float* __restrict__ tbb,
                                                        const float* __restrict__ dsi,
                                                        const float* __restrict__ dti,
                                                        __half* __restrict__ As,
                                                        __half* __restrict__ At, int n) {
    int y = blockIdx.y;
    const float* X = y ? Xt : Xs;
    const float* Wset[2] = { y ? tWa : sWa, y ? tWb : sWb };
    const float* bset[2] = { y ? tba : sba, y ? tbb : sbb };
    const float* scale = y ? dti : dsi;
    __half* A = y ? At : As;

    __shared__ float stage[4][2][16][68];   // [wave][set][node][col]

    int tid = threadIdx.x;
    int w = tid >> 6, lane = tid & 63;
    int quad = lane >> 4, col = lane & 15;
    int node0 = blockIdx.x * 64 + w * 16;

    half8 afrag[4];
    {
        int row = node0 + col;
        if (row >= n) row = n - 1;
        const float* xr = X + (size_t)row * 128 + quad * 8;
#pragma unroll
        for (int kc = 0; kc < 4; ++kc) {
            float4 f0 = *(const float4*)(xr + kc * 32);
            float4 f1 = *(const float4*)(xr + kc * 32 + 4);
            half8 h;
            h[0] = (_Float16)f0.x; h[1] = (_Float16)f0.y;
            h[2] = (_Float16)f0.z; h[3] = (_Float16)f0.w;
            h[4] = (_Float16)f1.x; h[5] = (_Float16)f1.y;
            h[6] = (_Float16)f1.z; h[7] = (_Float16)f1.w;
            afrag[kc] = h;
        }
    }

#pragma unroll
    for (int set = 0; set < 2; ++set) {
        const float* Ws = Wset[set];
#pragma unroll
        for (int nt = 0; nt < 4; ++nt) {
            float bb = bset[set][nt * 16 + col];
            f32x4 acc = { bb, bb, bb, bb };
            const float* wr = Ws + (size_t)(nt * 16 + col) * 128 + quad * 8;
#pragma unroll
            for (int kc = 0; kc < 4; ++kc) {
                float4 f0 = *(const float4*)(wr + kc * 32);
                float4 f1 = *(const float4*)(wr + kc * 32 + 4);
                half8 bfr;
                bfr[0] = (_Float16)f0.x; bfr[1] = (_Float16)f0.y;
                bfr[2] = (_Float16)f0.z; bfr[3] = (_Float16)f0.w;
                bfr[4] = (_Float16)f1.x; bfr[5] = (_Float16)f1.y;
                bfr[6] = (_Float16)f1.z; bfr[7] = (_Float16)f1.w;
                acc = __builtin_amdgcn_mfma_f32_16x16x32_f16(afrag[kc], bfr, acc, 0, 0, 0);
            }
#pragma unroll
            for (int r = 0; r < 4; ++r)
                stage[w][set][quad * 4 + r][nt * 16 + col] = acc[r];
        }
    }
    __syncthreads();

    int mrow = lane >> 3;     // 0..7
    int chunk = lane & 7;     // 8 halves per chunk
#pragma unroll
    for (int rnd = 0; rnd < 2; ++rnd) {
        int m = mrow + rnd * 8;
        int node = node0 + m;
        if (node < n) {
            float sc = scale[node];
#pragma unroll
            for (int set = 0; set < 2; ++set) {
                const float* src = &stage[w][set][m][chunk * 8];
                float4 f0 = *(const float4*)src;
                float4 f1 = *(const float4*)(src + 4);
                __half2 h0 = __floats2half2_rn(sc * f0.x, sc * f0.y);
                __half2 h1 = __floats2half2_rn(sc * f0.z, sc * f0.w);
                __half2 h2 = __floats2half2_rn(sc * f1.x, sc * f1.y);
                __half2 h3 = __floats2half2_rn(sc * f1.z, sc * f1.w);
                uint4 u;
                u.x = *(unsigned int*)&h0; u.y = *(unsigned int*)&h1;
                u.z = *(unsigned int*)&h2; u.w = *(unsigned int*)&h3;
                *(uint4*)(A + (size_t)node * 128 + set * 64 + chunk * 8) = u;
            }
        }
    }
}

__device__ inline void acc_h8(float* acc, uint4 u) {
    const __half2* h = (const __half2*)&u;
    float2 f0 = __half22float2(h[0]);
    float2 f1 = __half22float2(h[1]);
    float2 f2 = __half22float2(h[2]);
    float2 f3 = __half22float2(h[3]);
    acc[0] += f0.x; acc[1] += f0.y; acc[2] += f1.x; acc[3] += f1.y;
    acc[4] += f2.x; acc[5] += f2.y; acc[6] += f3.x; acc[7] += f3.y;
}

// ======= fused conv1-aggregate + relu + conv2 dual linear; s/t via blockIdx.y =======
// 8-deep gather unroll: 2 uint2 pay loads + 8 independent uint4 gathers in flight.
__global__ __launch_bounds__(256) void pull_lin2_kernel(const __half* __restrict__ As,
                                                        const __half* __restrict__ At,
                                                        __half* __restrict__ Cs,
                                                        __half* __restrict__ Ct,
                                                        const int* __restrict__ offs_f,
                                                        const int* __restrict__ offs_b,
                                                        const unsigned short* __restrict__ pay_f,
                                                        const unsigned short* __restrict__ pay_b,
                                                        const float* __restrict__ dsi,
                                                        const float* __restrict__ dti,
                                                        const float* __restrict__ sW2a,
                                                        const float* __restrict__ sb2a,
                                                        const float* __restrict__ sW2b,
                                                        const float* __restrict__ sb2b,
                                                        const float* __restrict__ tW2a,
                                                        const float* __restrict__ tb2a,
                                                        const float* __restrict__ tW2b,
                                                        const float* __restrict__ tb2b, int n) {
    int y = blockIdx.y;
    const __half* xw = y ? At : As;
    __half* C = y ? Ct : Cs;
    const int* offs = y ? offs_b : offs_f;
    const unsigned short* pay = y ? pay_b : pay_f;
    const float* fac_self = y ? dsi : dti;
    const float* scale2   = y ? dsi : dti;
    const float* W2a = y ? tW2a : sW2a;  const float* b2a = y ? tb2a : sb2a;
    const float* W2b = y ? tW2b : sW2b;  const float* b2b = y ? tb2b : sb2b;

    __shared__ float Wt[64 * 66];
    __shared__ float bsh[64];
    __shared__ float xs[16 * 132];

    int tid = threadIdx.x;
    for (int idx = tid; idx < 2048; idx += 256) {   // overlaps gather latency
        int o = idx >> 6, k = idx & 63;
        Wt[k * 66 + o]      = W2a[idx];
        Wt[k * 66 + 33 + o] = W2b[idx];
    }
    if (tid < 32) { bsh[tid] = b2a[tid]; bsh[32 + tid] = b2b[tid]; }

    int ln = tid >> 4;     // node slot 0..15
    int f4 = tid & 15;     // uint4 column (8 halves)
    int v = blockIdx.x * 16 + ln;
    int i = offs[v], end = offs[v + 1];
    const uint4* xw16 = (const uint4*)xw;           // row stride = 16 uint4

    float acc[8] = {0, 0, 0, 0, 0, 0, 0, 0};
    acc_h8(acc, xw16[v * 16 + f4]);                 // self-loop row (pre-scaled)
    while (i < end && (i & 3)) {                    // align to 8B pay boundary
        acc_h8(acc, xw16[pay[i] * 16 + f4]);
        ++i;
    }
    for (; i + 7 < end; i += 8) {                   // 8 independent gathers in flight
        uint2 pk0 = *(const uint2*)(pay + i);
        uint2 pk1 = *(const uint2*)(pay + i + 4);
        int s0 = pk0.x & 0xffff, s1 = pk0.x >> 16;
        int s2 = pk0.y & 0xffff, s3 = pk0.y >> 16;
        int s4 = pk1.x & 0xffff, s5 = pk1.x >> 16;
        int s6 = pk1.y & 0xffff, s7 = pk1.y >> 16;
        uint4 ua = xw16[s0 * 16 + f4];
        uint4 ub = xw16[s1 * 16 + f4];
        uint4 uc = xw16[s2 * 16 + f4];
        uint4 ud = xw16[s3 * 16 + f4];
        uint4 ue = xw16[s4 * 16 + f4];
        uint4 uf = xw16[s5 * 16 + f4];
        uint4 ug = xw16[s6 * 16 + f4];
        uint4 uh = xw16[s7 * 16 + f4];
        acc_h8(acc, ua); acc_h8(acc, ub); acc_h8(acc, uc); acc_h8(acc, ud);
        acc_h8(acc, ue); acc_h8(acc, uf); acc_h8(acc, ug); acc_h8(acc, uh);
    }
    if (i + 3 < end) {
        uint2 pk = *(const uint2*)(pay + i);
        int s0 = pk.x & 0xffff, s1 = pk.x >> 16;
        int s2 = pk.y & 0xffff, s3 = pk.y >> 16;
        uint4 ua = xw16[s0 * 16 + f4];
        uint4 ub = xw16[s1 * 16 + f4];
        uint4 uc = xw16[s2 * 16 + f4];
        uint4 ud = xw16[s3 * 16 + f4];
        acc_h8(acc, ua); acc_h8(acc, ub); acc_h8(acc, uc); acc_h8(acc, ud);
        i += 4;
    }
    for (; i < end; ++i) acc_h8(acc, xw16[pay[i] * 16 + f4]);

    float fs = fac_self[v];
    float4 a0, a1;
    a0.x = fmaxf(acc[0] * fs, 0.0f); a0.y = fmaxf(acc[1] * fs, 0.0f);
    a0.z = fmaxf(acc[2] * fs, 0.0f); a0.w = fmaxf(acc[3] * fs, 0.0f);
    a1.x = fmaxf(acc[4] * fs, 0.0f); a1.y = fmaxf(acc[5] * fs, 0.0f);
    a1.z = fmaxf(acc[6] * fs, 0.0f); a1.w = fmaxf(acc[7] * fs, 0.0f);
    *(float4*)&xs[ln * 132 + f4 * 8]     = a0;
    *(float4*)&xs[ln * 132 + f4 * 8 + 4] = a1;
    __syncthreads();

    int nn = tid >> 5, o = tid & 31;
    const float* x0 = &xs[nn * 132];
    const float* x1 = &xs[(nn + 8) * 132];
    float am0 = bsh[o], al0 = bsh[32 + o];
    float am1 = am0,    al1 = al0;
#pragma unroll 4
    for (int k = 0; k < 64; ++k) {
        float wm = Wt[k * 66 + o], wl = Wt[k * 66 + 33 + o];
        am0 += x0[k] * wm;  al0 += x0[64 + k] * wl;
        am1 += x1[k] * wm;  al1 += x1[64 + k] * wl;
    }
    int v0 = blockIdx.x * 16 + nn;
    int v1 = v0 + 8;
    float sc0 = scale2[v0], sc1 = scale2[v1];
    C[v0 * 64 + o]      = __float2half(sc0 * am0);
    C[v0 * 64 + 32 + o] = __float2half(sc0 * al0);
    C[v1 * 64 + o]      = __float2half(sc1 * am1);
    C[v1 * 64 + 32 + o] = __float2half(sc1 * al1);
}

// ================= final pull + reparametrize; s/t via blockIdx.y =================
__global__ __launch_bounds__(256) void final_pull2_kernel(const __half* __restrict__ Cs,
                                                          const __half* __restrict__ Ct,
                                                          float* __restrict__ out_s,
                                                          float* __restrict__ out_t,
                                                          const int* __restrict__ offs_f,
                                                          const int* __restrict__ offs_b,
                                                          const unsigned short* __restrict__ pay_f,
                                                          const unsigned short* __restrict__ pay_b,
                                                          const float* __restrict__ dsi,
                                                          const float* __restrict__ dti,
                                                          const float* __restrict__ noise_s,
                                                          const float* __restrict__ noise_t,
                                                          int n) {
    int y = blockIdx.y;
    const __half* xw = y ? Ct : Cs;
    float* out = y ? out_t : out_s;
    const int* offs = y ? offs_f : offs_b;                  // NOTE: flipped vs conv1
    const unsigned short* pay = y ? pay_f : pay_b;
    const float* fac_self = y ? dti : dsi;
    const float* noise = y ? noise_t : noise_s;

    const uint4* xw16 = (const uint4*)xw;           // row stride = 8 uint4 (64 halves)
    int ln = threadIdx.x >> 3;
    int f4 = threadIdx.x & 7;
    int v = blockIdx.x * 32 + ln;
    if (v >= n) return;
    int i = offs[v], end = offs[v + 1];

    float acc[8] = {0, 0, 0, 0, 0, 0, 0, 0};
    acc_h8(acc, xw16[v * 8 + f4]);
    while (i < end && (i & 3)) {
        acc_h8(acc, xw16[pay[i] * 8 + f4]);
        ++i;
    }
    for (; i + 7 < end; i += 8) {
        uint2 pk0 = *(const uint2*)(pay + i);
        uint2 pk1 = *(const uint2*)(pay + i + 4);
        int s0 = pk0.x & 0xffff, s1 = pk0.x >> 16;
        int s2 = pk0.y & 0xffff, s3 = pk0.y >> 16;
        int s4 = pk1.x & 0xffff, s5 = pk1.x >> 16;
        int s6 = pk1.y & 0xffff, s7 = pk1.y >> 16;
        uint4 ua = xw16[s0 * 8 + f4];
        uint4 ub = xw16[s1 * 8 + f4];
        uint4 uc = xw16[s2 * 8 + f4];
        uint4 ud = xw16[s3 * 8 + f4];
        uint4 ue = xw16[s4 * 8 + f4];
        uint4 uf = xw16[s5 * 8 + f4];
        uint4 ug = xw16[s6 * 8 + f4];
        uint4 uh = xw16[s7 * 8 + f4];
        acc_h8(acc, ua); acc_h8(acc, ub); acc_h8(acc, uc); acc_h8(acc, ud);
        acc_h8(acc, ue); acc_h8(acc, uf); acc_h8(acc, ug); acc_h8(acc, uh);
    }
    if (i + 3 < end) {
        uint2 pk = *(const uint2*)(pay + i);
        int s0 = pk.x & 0xffff, s1 = pk.x >> 16;
        int s2 = pk.y & 0xffff, s3 = pk.y >> 16;
        uint4 ua = xw16[s0 * 8 + f4];
        uint4 ub = xw16[s1 * 8 + f4];
        uint4 uc = xw16[s2 * 8 + f4];
        uint4 ud = xw16[s3 * 8 + f4];
        acc_h8(acc, ua); acc_h8(acc, ub); acc_h8(acc, uc); acc_h8(acc, ud);
        i += 4;
    }
    for (; i < end; ++i) acc_h8(acc, xw16[pay[i] * 8 + f4]);

    float fs = fac_self[v];
#pragma unroll
    for (int j = 0; j < 8; ++j) acc[j] *= fs;

    int lane = threadIdx.x & 63;
    float lg[8];
#pragma unroll
    for (int j = 0; j < 8; ++j) lg[j] = __shfl(acc[j], lane + 4);
    if (f4 < 4) {
        const float4* nz4 = (const float4*)noise;
        float4 n0 = nz4[v * 8 + f4 * 2];
        float4 n1 = nz4[v * 8 + f4 * 2 + 1];
        float4 r0, r1;
        r0.x = acc[0] + n0.x * expf(lg[0]) * 0.2f;
        r0.y = acc[1] + n0.y * expf(lg[1]) * 0.2f;
        r0.z = acc[2] + n0.z * expf(lg[2]) * 0.2f;
        r0.w = acc[3] + n0.w * expf(lg[3]) * 0.2f;
        r1.x = acc[4] + n1.x * expf(lg[4]) * 0.2f;
        r1.y = acc[5] + n1.y * expf(lg[5]) * 0.2f;
        r1.z = acc[6] + n1.z * expf(lg[6]) * 0.2f;
        r1.w = acc[7] + n1.w * expf(lg[7]) * 0.2f;
        float4* o4 = (float4*)out;
        o4[v * 8 + f4 * 2]     = r0;
        o4[v * 8 + f4 * 2 + 1] = r1;
    }
}

// ================= driver =================
extern "C" void kernel_launch(void* const* d_in, const int* in_sizes, int n_in,
                              void* d_out, int out_size, void* d_ws, size_t ws_size,
                              hipStream_t stream) {
    const float* s       = (const float*)d_in[0];
    const float* t       = (const float*)d_in[1];
    const int*   ei      = (const int*)d_in[2];
    const float* noise_s = (const float*)d_in[3];
    const float* noise_t = (const float*)d_in[4];
    const float* sm1_W = (const float*)d_in[5];  const float* sm1_b = (const float*)d_in[6];
    const float* sm2_W = (const float*)d_in[7];  const float* sm2_b = (const float*)d_in[8];
    const float* sl1_W = (const float*)d_in[9];  const float* sl1_b = (const float*)d_in[10];
    const float* sl2_W = (const float*)d_in[11]; const float* sl2_b = (const float*)d_in[12];
    const float* tm1_W = (const float*)d_in[13]; const float* tm1_b = (const float*)d_in[14];
    const float* tm2_W = (const float*)d_in[15]; const float* tm2_b = (const float*)d_in[16];
    const float* tl1_W = (const float*)d_in[17]; const float* tl1_b = (const float*)d_in[18];
    const float* tl2_W = (const float*)d_in[19]; const float* tl2_b = (const float*)d_in[20];

    const int* ei0 = ei;            // sources
    const int* ei1 = ei + E_EDGES;  // targets

    __half* A_s = (__half*)d_ws;                       // [N][128]
    __half* A_t = A_s + (size_t)N_NODES * 128;         // [N][128]
    __half* C_s = A_t + (size_t)N_NODES * 128;         // [N][64]
    __half* C_t = C_s + (size_t)N_NODES * 64;          // [N][64]
    float* dsi = (float*)(C_t + (size_t)N_NODES * 64); // N
    float* dti = dsi + N_NODES;                        // N
    int* offs_fwd = (int*)(dti + N_NODES);             // N+1
    int* offs_bwd = offs_fwd + N_NODES + 1;            // N+1
    int* cnt_fwd  = offs_bwd + N_NODES + 1;            // N
    int* cnt_bwd  = cnt_fwd + N_NODES;                 // N
    int* rank_fwd = cnt_bwd + N_NODES;                 // E
    int* rank_bwd = rank_fwd + E_EDGES;                // E
    int* part_fwd = rank_bwd + E_EDGES;                // NCHUNKS+1
    int* part_bwd = part_fwd + NCHUNKS + 1;            // NCHUNKS+1
    unsigned short* pay_fwd = (unsigned short*)(part_bwd + NCHUNKS + 1);  // E
    unsigned short* pay_bwd = pay_fwd + E_EDGES;                          // E

    float* s_out = (float*)d_out;
    float* t_out = (float*)d_out + N_NODES * 32;

    dim3 blk(256);
    int ngrid = (N_NODES + 255) / 256;
    int egrid = (E_EDGES + 255) / 256;
    dim3 agrid((N_NODES + 1 + 255) / 256, 2);
    dim3 mgrid((N_NODES + 63) / 64, 2);    // 782 x 2 (MFMA lin1: 64 nodes/block)
    dim3 pgrid(N_NODES / 16, 2);           // 3125 x 2
    dim3 fgrid((N_NODES + 31) / 32, 2);    // 1563 x 2

    // ---- CSR + degrees ----
    zero2_kernel<<<ngrid, blk, 0, stream>>>(cnt_fwd, cnt_bwd, N_NODES);
    count_rank_kernel<<<egrid, blk, 0, stream>>>(ei0, ei1, cnt_fwd, cnt_bwd,
                                                 rank_fwd, rank_bwd, E_EDGES);
    scan_chunk2_kernel<<<dim3(NCHUNKS, 2), 1024, 0, stream>>>(
        cnt_fwd, cnt_bwd, offs_fwd, offs_bwd, part_fwd, part_bwd, N_NODES);
    scan_partials2_kernel<<<2, 64, 0, stream>>>(part_fwd, part_bwd, NCHUNKS);
    addback_deg_kernel<<<agrid, blk, 0, stream>>>(offs_fwd, offs_bwd, part_fwd, part_bwd,
                                                  cnt_fwd, cnt_bwd, dsi, dti,
                                                  N_NODES, NCHUNKS);
    fill2_kernel<<<dim3(egrid, 2), blk, 0, stream>>>(ei0, ei1, rank_fwd, rank_bwd,
                                                     offs_fwd, offs_bwd, pay_fwd, pay_bwd,
                                                     E_EDGES);

    // ---- both encoder pairs, s/t merged per phase ----
    lin1_mfma_kernel<<<mgrid, blk, 0, stream>>>(s, t,
                                                sm1_W, sm1_b, sl1_W, sl1_b,
                                                tm1_W, tm1_b, tl1_W, tl1_b,
                                                dsi, dti, A_s, A_t, N_NODES);
    pull_lin2_kernel<<<pgrid, blk, 0, stream>>>(A_s, A_t, C_s, C_t,
                                                offs_fwd, offs_bwd, pay_fwd, pay_bwd,
                                                dsi, dti,
                                                sm2_W, sm2_b, sl2_W, sl2_b,
                                                tm2_W, tm2_b, tl2_W, tl2_b, N_NODES);
    final_pull2_kernel<<<fgrid, blk, 0, stream>>>(C_s, C_t, s_out, t_out,
                                                  offs_fwd, offs_bwd, pay_fwd, pay_bwd,
                                                  dsi, dti, noise_s, noise_t, N_NODES);
}

// Round 11
// 361.824 us; speedup vs baseline: 1.0627x; 1.0627x over previous
//
#include <hip/hip_runtime.h>
#include <hip/hip_fp16.h>
#include <math.h>

#define N_NODES 50000
#define E_EDGES 800000
#define NCHUNKS ((N_NODES + 1023) / 1024)
#define LIN_BLOCKS 1564              // 782 x-blocks * 2 (s/t)
#define CNT_BLOCKS 3125              // ceil(E/256)

typedef _Float16 half8 __attribute__((ext_vector_type(8)));
typedef float f32x4 __attribute__((ext_vector_type(4)));

__device__ inline float fac_from(unsigned int u) {
    unsigned short us = (unsigned short)(u >> 16);
    __half h;
    __builtin_memcpy(&h, &us, 2);
    return __half2float(h);
}

// ================= CSR build =================
__global__ __launch_bounds__(256) void zero2_kernel(int* a, int* b, int n) {
    int t = blockIdx.x * 256 + threadIdx.x;
    if (t < n) { a[t] = 0; b[t] = 0; }
}

// ===== FUSED: edge degree-count+rank (atomic pipe) + conv1 dual-linear MFMA =====
// role by blockIdx.x % 3: {0,2}=count (2:1 interleave), {1}=lin1.
// lin1 stores UNSCALED fp16 A rows (norm factor applied gather-side via packed pay),
// so it has no dependency on degrees -> can overlap the atomic-bound count.
__global__ __launch_bounds__(256) void count_lin1_kernel(const int* __restrict__ ei0,
                                                         const int* __restrict__ ei1,
                                                         int* cnt_fwd, int* cnt_bwd,
                                                         int* rank_fwd, int* rank_bwd,
                                                         const float* __restrict__ Xs,
                                                         const float* __restrict__ Xt,
                                                         const float* __restrict__ sWa,
                                                         const float* __restrict__ sba,
                                                         const float* __restrict__ sWb,
                                                         const float* __restrict__ sbb,
                                                         const float* __restrict__ tWa,
                                                         const float* __restrict__ tba,
                                                         const float* __restrict__ tWb,
                                                         const float* __restrict__ tbb,
                                                         __half* __restrict__ As,
                                                         __half* __restrict__ At, int n) {
    int bx = blockIdx.x;
    int tid = threadIdx.x;
    if (bx % 3 != 1) {
        // ---------------- count role ----------------
        int cidx = (bx / 3) * 2 + (bx % 3 == 2 ? 1 : 0);
        if (cidx >= CNT_BLOCKS) return;
        int t = cidx * 256 + tid;
        if (t < E_EDGES) {
            rank_fwd[t] = atomicAdd(&cnt_fwd[ei1[t]], 1);   // indeg
            rank_bwd[t] = atomicAdd(&cnt_bwd[ei0[t]], 1);   // outdeg
        }
        return;
    }
    // ---------------- lin1 MFMA role (no LDS: direct D-layout stores) ----------------
    int lidx = bx / 3;                       // 0..1563
    int y = lidx & 1;
    int xb = lidx >> 1;                      // 0..781
    const float* X = y ? Xt : Xs;
    const float* Wset[2] = { y ? tWa : sWa, y ? tWb : sWb };
    const float* bset[2] = { y ? tba : sba, y ? tbb : sbb };
    __half* A = y ? At : As;

    int w = tid >> 6, lane = tid & 63;
    int quad = lane >> 4, col = lane & 15;
    int node0 = xb * 64 + w * 16;

    half8 afrag[4];
    {
        int row = node0 + col;
        if (row >= n) row = n - 1;
        const float* xr = X + (size_t)row * 128 + quad * 8;
#pragma unroll
        for (int kc = 0; kc < 4; ++kc) {
            float4 f0 = *(const float4*)(xr + kc * 32);
            float4 f1 = *(const float4*)(xr + kc * 32 + 4);
            half8 h;
            h[0] = (_Float16)f0.x; h[1] = (_Float16)f0.y;
            h[2] = (_Float16)f0.z; h[3] = (_Float16)f0.w;
            h[4] = (_Float16)f1.x; h[5] = (_Float16)f1.y;
            h[6] = (_Float16)f1.z; h[7] = (_Float16)f1.w;
            afrag[kc] = h;
        }
    }

#pragma unroll
    for (int set = 0; set < 2; ++set) {
        const float* Ws = Wset[set];
#pragma unroll
        for (int nt = 0; nt < 4; ++nt) {
            float bb = bset[set][nt * 16 + col];
            f32x4 acc = { bb, bb, bb, bb };
            const float* wr = Ws + (size_t)(nt * 16 + col) * 128 + quad * 8;
#pragma unroll
            for (int kc = 0; kc < 4; ++kc) {
                float4 f0 = *(const float4*)(wr + kc * 32);
                float4 f1 = *(const float4*)(wr + kc * 32 + 4);
                half8 bfr;
                bfr[0] = (_Float16)f0.x; bfr[1] = (_Float16)f0.y;
                bfr[2] = (_Float16)f0.z; bfr[3] = (_Float16)f0.w;
                bfr[4] = (_Float16)f1.x; bfr[5] = (_Float16)f1.y;
                bfr[6] = (_Float16)f1.z; bfr[7] = (_Float16)f1.w;
                acc = __builtin_amdgcn_mfma_f32_16x16x32_f16(afrag[kc], bfr, acc, 0, 0, 0);
            }
            // D: row = quad*4 + r, col = lane&15 -> direct fp16 store (unscaled)
#pragma unroll
            for (int r = 0; r < 4; ++r) {
                int node = node0 + quad * 4 + r;
                if (node < n)
                    A[(size_t)node * 128 + set * 64 + nt * 16 + col] = __float2half(acc[r]);
            }
        }
    }
}

// ---- grid-parallel exclusive scan, both directions via blockIdx.y ----
__global__ __launch_bounds__(1024) void scan_chunk2_kernel(const int* __restrict__ cnt_f,
                                                           const int* __restrict__ cnt_b,
                                                           int* __restrict__ offs_f,
                                                           int* __restrict__ offs_b,
                                                           int* __restrict__ part_f,
                                                           int* __restrict__ part_b, int n) {
    const int* cnt = blockIdx.y ? cnt_b : cnt_f;
    int* offs = blockIdx.y ? offs_b : offs_f;
    int* partials = blockIdx.y ? part_b : part_f;
    __shared__ int sh[1024];
    int tid = threadIdx.x;
    int i = blockIdx.x * 1024 + tid;
    int v = (i < n) ? cnt[i] : 0;
    sh[tid] = v;
    __syncthreads();
    for (int off = 1; off < 1024; off <<= 1) {
        int add = (tid >= off) ? sh[tid - off] : 0;
        __syncthreads();
        sh[tid] += add;
        __syncthreads();
    }
    if (i < n) offs[i] = sh[tid] - v;
    if (tid == 1023) partials[blockIdx.x] = sh[tid];
}

__global__ __launch_bounds__(64) void scan_partials2_kernel(int* part_f, int* part_b, int nchunks) {
    int* p = blockIdx.x ? part_b : part_f;
    __shared__ int sh[64];
    int tid = threadIdx.x;
    int v = (tid < nchunks) ? p[tid] : 0;
    sh[tid] = v;
    __syncthreads();
    for (int off = 1; off < 64; off <<= 1) {
        int add = (tid >= off) ? sh[tid - off] : 0;
        __syncthreads();
        sh[tid] += add;
        __syncthreads();
    }
    if (tid < nchunks) p[tid] = sh[tid] - v;
    if (tid == 63) p[nchunks] = sh[63];
}

__global__ __launch_bounds__(256) void addback_deg_kernel(int* __restrict__ offs_f,
                                                          int* __restrict__ offs_b,
                                                          const int* __restrict__ part_f,
                                                          const int* __restrict__ part_b,
                                                          const int* __restrict__ cnt_f,
                                                          const int* __restrict__ cnt_b,
                                                          float* dsi, float* dti,
                                                          int n, int nchunks) {
    int i = blockIdx.x * 256 + threadIdx.x;
    if (blockIdx.y == 0) {
        if (i < n) {
            offs_f[i] += part_f[i >> 10];
            dti[i] = rsqrtf((float)(cnt_f[i] + 1));
        } else if (i == n) offs_f[n] = part_f[nchunks];
    } else {
        if (i < n) {
            offs_b[i] += part_b[i >> 10];
            dsi[i] = rsqrtf((float)(cnt_b[i] + 1));
        } else if (i == n) offs_b[n] = part_b[nchunks];
    }
}

// fill packed payload: id | fp16(gather-side factor) << 16
__global__ __launch_bounds__(256) void fill2_kernel(const int* __restrict__ ei0,
                                                    const int* __restrict__ ei1,
                                                    const int* __restrict__ rank_f,
                                                    const int* __restrict__ rank_b,
                                                    const int* __restrict__ offs_f,
                                                    const int* __restrict__ offs_b,
                                                    const float* __restrict__ dsi,
                                                    const float* __restrict__ dti,
                                                    unsigned int* __restrict__ pay_f,
                                                    unsigned int* __restrict__ pay_b, int e) {
    int t = blockIdx.x * 256 + threadIdx.x;
    if (t >= e) return;
    if (blockIdx.y == 0) {
        int id = ei0[t];                         // payload = src
        __half h = __float2half(dsi[id]);
        unsigned short hb; __builtin_memcpy(&hb, &h, 2);
        pay_f[offs_f[ei1[t]] + rank_f[t]] = (unsigned int)id | ((unsigned int)hb << 16);
    } else {
        int id = ei1[t];                         // payload = dst
        __half h = __float2half(dti[id]);
        unsigned short hb; __builtin_memcpy(&hb, &h, 2);
        pay_b[offs_b[ei0[t]] + rank_b[t]] = (unsigned int)id | ((unsigned int)hb << 16);
    }
}

__device__ inline void acc_fma(float* acc, uint4 u, float f) {
    const __half2* h = (const __half2*)&u;
    float2 f0 = __half22float2(h[0]);
    float2 f1 = __half22float2(h[1]);
    float2 f2 = __half22float2(h[2]);
    float2 f3 = __half22float2(h[3]);
    acc[0] += f * f0.x; acc[1] += f * f0.y; acc[2] += f * f1.x; acc[3] += f * f1.y;
    acc[4] += f * f2.x; acc[5] += f * f2.y; acc[6] += f * f3.x; acc[7] += f * f3.y;
}

// ======= fused conv1-aggregate + relu + conv2 dual linear; s/t via blockIdx.y =======
// A rows UNSCALED; per-edge factor comes packed in pay (no dependent load).
__global__ __launch_bounds__(256) void pull_lin2_kernel(const __half* __restrict__ As,
                                                        const __half* __restrict__ At,
                                                        __half* __restrict__ Cs,
                                                        __half* __restrict__ Ct,
                                                        const int* __restrict__ offs_f,
                                                        const int* __restrict__ offs_b,
                                                        const unsigned int* __restrict__ pay_f,
                                                        const unsigned int* __restrict__ pay_b,
                                                        const float* __restrict__ dsi,
                                                        const float* __restrict__ dti,
                                                        const float* __restrict__ sW2a,
                                                        const float* __restrict__ sb2a,
                                                        const float* __restrict__ sW2b,
                                                        const float* __restrict__ sb2b,
                                                        const float* __restrict__ tW2a,
                                                        const float* __restrict__ tb2a,
                                                        const float* __restrict__ tW2b,
                                                        const float* __restrict__ tb2b, int n) {
    int y = blockIdx.y;
    const __half* xw = y ? At : As;
    __half* C = y ? Ct : Cs;
    const int* offs = y ? offs_b : offs_f;
    const unsigned int* pay = y ? pay_b : pay_f;
    const float* fac_self  = y ? dsi : dti;   // fwd: dti, bwd: dsi
    const float* fac_other = y ? dti : dsi;   // self-loop gather factor
    const float* W2a = y ? tW2a : sW2a;  const float* b2a = y ? tb2a : sb2a;
    const float* W2b = y ? tW2b : sW2b;  const float* b2b = y ? tb2b : sb2b;

    __shared__ float Wt[64 * 66];
    __shared__ float bsh[64];
    __shared__ float xs[16 * 132];

    int tid = threadIdx.x;
    for (int idx = tid; idx < 2048; idx += 256) {   // overlaps gather latency
        int o = idx >> 6, k = idx & 63;
        Wt[k * 66 + o]      = W2a[idx];
        Wt[k * 66 + 33 + o] = W2b[idx];
    }
    if (tid < 32) { bsh[tid] = b2a[tid]; bsh[32 + tid] = b2b[tid]; }

    int ln = tid >> 4;     // node slot 0..15
    int f4 = tid & 15;     // uint4 column (8 halves)
    int v = blockIdx.x * 16 + ln;
    int i = offs[v], end = offs[v + 1];
    const uint4* xw16 = (const uint4*)xw;           // row stride = 16 uint4

    float acc[8] = {0, 0, 0, 0, 0, 0, 0, 0};
    acc_fma(acc, xw16[v * 16 + f4], fac_other[v]);  // self-loop
    while (i < end && (i & 3)) {                    // align to 16B pay boundary
        unsigned int pk = pay[i];
        acc_fma(acc, xw16[(pk & 0xffff) * 16 + f4], fac_from(pk));
        ++i;
    }
    for (; i + 3 < end; i += 4) {                   // 1 uint4 pay load + 4 gathers
        uint4 pk = *(const uint4*)(pay + i);
        int s0 = pk.x & 0xffff, s1 = pk.y & 0xffff;
        int s2 = pk.z & 0xffff, s3 = pk.w & 0xffff;
        uint4 ua = xw16[s0 * 16 + f4];
        uint4 ub = xw16[s1 * 16 + f4];
        uint4 uc = xw16[s2 * 16 + f4];
        uint4 ud = xw16[s3 * 16 + f4];
        acc_fma(acc, ua, fac_from(pk.x));
        acc_fma(acc, ub, fac_from(pk.y));
        acc_fma(acc, uc, fac_from(pk.z));
        acc_fma(acc, ud, fac_from(pk.w));
    }
    for (; i < end; ++i) {
        unsigned int pk = pay[i];
        acc_fma(acc, xw16[(pk & 0xffff) * 16 + f4], fac_from(pk));
    }

    float fs = fac_self[v];
    float4 a0, a1;
    a0.x = fmaxf(acc[0] * fs, 0.0f); a0.y = fmaxf(acc[1] * fs, 0.0f);
    a0.z = fmaxf(acc[2] * fs, 0.0f); a0.w = fmaxf(acc[3] * fs, 0.0f);
    a1.x = fmaxf(acc[4] * fs, 0.0f); a1.y = fmaxf(acc[5] * fs, 0.0f);
    a1.z = fmaxf(acc[6] * fs, 0.0f); a1.w = fmaxf(acc[7] * fs, 0.0f);
    *(float4*)&xs[ln * 132 + f4 * 8]     = a0;
    *(float4*)&xs[ln * 132 + f4 * 8 + 4] = a1;
    __syncthreads();

    // conv2 dual linear; C rows stored UNSCALED (factor applied at final gather)
    int nn = tid >> 5, o = tid & 31;
    const float* x0 = &xs[nn * 132];
    const float* x1 = &xs[(nn + 8) * 132];
    float am0 = bsh[o], al0 = bsh[32 + o];
    float am1 = am0,    al1 = al0;
#pragma unroll 4
    for (int k = 0; k < 64; ++k) {
        float wm = Wt[k * 66 + o], wl = Wt[k * 66 + 33 + o];
        am0 += x0[k] * wm;  al0 += x0[64 + k] * wl;
        am1 += x1[k] * wm;  al1 += x1[64 + k] * wl;
    }
    int v0 = blockIdx.x * 16 + nn;
    int v1 = v0 + 8;
    C[v0 * 64 + o]      = __float2half(am0);
    C[v0 * 64 + 32 + o] = __float2half(al0);
    C[v1 * 64 + o]      = __float2half(am1);
    C[v1 * 64 + 32 + o] = __float2half(al1);
}

// ================= final pull + reparametrize; s/t via blockIdx.y =================
__global__ __launch_bounds__(256) void final_pull2_kernel(const __half* __restrict__ Cs,
                                                          const __half* __restrict__ Ct,
                                                          float* __restrict__ out_s,
                                                          float* __restrict__ out_t,
                                                          const int* __restrict__ offs_f,
                                                          const int* __restrict__ offs_b,
                                                          const unsigned int* __restrict__ pay_f,
                                                          const unsigned int* __restrict__ pay_b,
                                                          const float* __restrict__ dsi,
                                                          const float* __restrict__ dti,
                                                          const float* __restrict__ noise_s,
                                                          const float* __restrict__ noise_t,
                                                          int n) {
    int y = blockIdx.y;
    const __half* xw = y ? Ct : Cs;
    float* out = y ? out_t : out_s;
    const int* offs = y ? offs_f : offs_b;                  // flipped vs conv1
    const unsigned int* pay = y ? pay_f : pay_b;
    const float* fac_self  = y ? dti : dsi;
    const float* fac_other = y ? dsi : dti;                 // self-loop gather factor
    const float* noise = y ? noise_t : noise_s;

    const uint4* xw16 = (const uint4*)xw;           // row stride = 8 uint4 (64 halves)
    int ln = threadIdx.x >> 3;
    int f4 = threadIdx.x & 7;
    int v = blockIdx.x * 32 + ln;
    if (v >= n) return;
    int i = offs[v], end = offs[v + 1];

    float acc[8] = {0, 0, 0, 0, 0, 0, 0, 0};
    acc_fma(acc, xw16[v * 8 + f4], fac_other[v]);
    while (i < end && (i & 3)) {
        unsigned int pk = pay[i];
        acc_fma(acc, xw16[(pk & 0xffff) * 8 + f4], fac_from(pk));
        ++i;
    }
    for (; i + 3 < end; i += 4) {
        uint4 pk = *(const uint4*)(pay + i);
        int s0 = pk.x & 0xffff, s1 = pk.y & 0xffff;
        int s2 = pk.z & 0xffff, s3 = pk.w & 0xffff;
        uint4 ua = xw16[s0 * 8 + f4];
        uint4 ub = xw16[s1 * 8 + f4];
        uint4 uc = xw16[s2 * 8 + f4];
        uint4 ud = xw16[s3 * 8 + f4];
        acc_fma(acc, ua, fac_from(pk.x));
        acc_fma(acc, ub, fac_from(pk.y));
        acc_fma(acc, uc, fac_from(pk.z));
        acc_fma(acc, ud, fac_from(pk.w));
    }
    for (; i < end; ++i) {
        unsigned int pk = pay[i];
        acc_fma(acc, xw16[(pk & 0xffff) * 8 + f4], fac_from(pk));
    }

    float fs = fac_self[v];
#pragma unroll
    for (int j = 0; j < 8; ++j) acc[j] *= fs;

    // lanes f4 0..3 hold mu cols; partner lane f4+4 holds logstd cols
    int lane = threadIdx.x & 63;
    float lg[8];
#pragma unroll
    for (int j = 0; j < 8; ++j) lg[j] = __shfl(acc[j], lane + 4);
    if (f4 < 4) {
        const float4* nz4 = (const float4*)noise;
        float4 n0 = nz4[v * 8 + f4 * 2];
        float4 n1 = nz4[v * 8 + f4 * 2 + 1];
        float4 r0, r1;
        r0.x = acc[0] + n0.x * expf(lg[0]) * 0.2f;
        r0.y = acc[1] + n0.y * expf(lg[1]) * 0.2f;
        r0.z = acc[2] + n0.z * expf(lg[2]) * 0.2f;
        r0.w = acc[3] + n0.w * expf(lg[3]) * 0.2f;
        r1.x = acc[4] + n1.x * expf(lg[4]) * 0.2f;
        r1.y = acc[5] + n1.y * expf(lg[5]) * 0.2f;
        r1.z = acc[6] + n1.z * expf(lg[6]) * 0.2f;
        r1.w = acc[7] + n1.w * expf(lg[7]) * 0.2f;
        float4* o4 = (float4*)out;
        o4[v * 8 + f4 * 2]     = r0;
        o4[v * 8 + f4 * 2 + 1] = r1;
    }
}

// ================= driver =================
extern "C" void kernel_launch(void* const* d_in, const int* in_sizes, int n_in,
                              void* d_out, int out_size, void* d_ws, size_t ws_size,
                              hipStream_t stream) {
    const float* s       = (const float*)d_in[0];
    const float* t       = (const float*)d_in[1];
    const int*   ei      = (const int*)d_in[2];
    const float* noise_s = (const float*)d_in[3];
    const float* noise_t = (const float*)d_in[4];
    const float* sm1_W = (const float*)d_in[5];  const float* sm1_b = (const float*)d_in[6];
    const float* sm2_W = (const float*)d_in[7];  const float* sm2_b = (const float*)d_in[8];
    const float* sl1_W = (const float*)d_in[9];  const float* sl1_b = (const float*)d_in[10];
    const float* sl2_W = (const float*)d_in[11]; const float* sl2_b = (const float*)d_in[12];
    const float* tm1_W = (const float*)d_in[13]; const float* tm1_b = (const float*)d_in[14];
    const float* tm2_W = (const float*)d_in[15]; const float* tm2_b = (const float*)d_in[16];
    const float* tl1_W = (const float*)d_in[17]; const float* tl1_b = (const float*)d_in[18];
    const float* tl2_W = (const float*)d_in[19]; const float* tl2_b = (const float*)d_in[20];

    const int* ei0 = ei;            // sources
    const int* ei1 = ei + E_EDGES;  // targets

    __half* A_s = (__half*)d_ws;                       // [N][128] unscaled fp16
    __half* A_t = A_s + (size_t)N_NODES * 128;         // [N][128]
    __half* C_s = A_t + (size_t)N_NODES * 128;         // [N][64] unscaled fp16
    __half* C_t = C_s + (size_t)N_NODES * 64;          // [N][64]
    unsigned int* pay_fwd = (unsigned int*)(C_t + (size_t)N_NODES * 64);  // E (16B-aligned)
    unsigned int* pay_bwd = pay_fwd + E_EDGES;                            // E
    float* dsi = (float*)(pay_bwd + E_EDGES);          // N
    float* dti = dsi + N_NODES;                        // N
    int* offs_fwd = (int*)(dti + N_NODES);             // N+1
    int* offs_bwd = offs_fwd + N_NODES + 1;            // N+1
    int* cnt_fwd  = offs_bwd + N_NODES + 1;            // N
    int* cnt_bwd  = cnt_fwd + N_NODES;                 // N
    int* rank_fwd = cnt_bwd + N_NODES;                 // E
    int* rank_bwd = rank_fwd + E_EDGES;                // E
    int* part_fwd = rank_bwd + E_EDGES;                // NCHUNKS+1
    int* part_bwd = part_fwd + NCHUNKS + 1;            // NCHUNKS+1   total ~52.5 MB

    float* s_out = (float*)d_out;
    float* t_out = (float*)d_out + N_NODES * 32;

    dim3 blk(256);
    int ngrid = (N_NODES + 255) / 256;
    int egrid = (E_EDGES + 255) / 256;
    dim3 agrid((N_NODES + 1 + 255) / 256, 2);
    dim3 pgrid(N_NODES / 16, 2);           // 3125 x 2
    dim3 fgrid((N_NODES + 31) / 32, 2);    // 1563 x 2

    // ---- CSR + degrees; lin1 MFMA overlapped with count atomics ----
    zero2_kernel<<<ngrid, blk, 0, stream>>>(cnt_fwd, cnt_bwd, N_NODES);
    count_lin1_kernel<<<3 * LIN_BLOCKS, blk, 0, stream>>>(
        ei0, ei1, cnt_fwd, cnt_bwd, rank_fwd, rank_bwd,
        s, t, sm1_W, sm1_b, sl1_W, sl1_b, tm1_W, tm1_b, tl1_W, tl1_b,
        A_s, A_t, N_NODES);
    scan_chunk2_kernel<<<dim3(NCHUNKS, 2), 1024, 0, stream>>>(
        cnt_fwd, cnt_bwd, offs_fwd, offs_bwd, part_fwd, part_bwd, N_NODES);
    scan_partials2_kernel<<<2, 64, 0, stream>>>(part_fwd, part_bwd, NCHUNKS);
    addback_deg_kernel<<<agrid, blk, 0, stream>>>(offs_fwd, offs_bwd, part_fwd, part_bwd,
                                                  cnt_fwd, cnt_bwd, dsi, dti,
                                                  N_NODES, NCHUNKS);
    fill2_kernel<<<dim3(egrid, 2), blk, 0, stream>>>(ei0, ei1, rank_fwd, rank_bwd,
                                                     offs_fwd, offs_bwd, dsi, dti,
                                                     pay_fwd, pay_bwd, E_EDGES);

    // ---- pulls (packed-factor gathers) ----
    pull_lin2_kernel<<<pgrid, blk, 0, stream>>>(A_s, A_t, C_s, C_t,
                                                offs_fwd, offs_bwd, pay_fwd, pay_bwd,
                                                dsi, dti,
                                                sm2_W, sm2_b, sl2_W, sl2_b,
                                                tm2_W, tm2_b, tl2_W, tl2_b, N_NODES);
    final_pull2_kernel<<<fgrid, blk, 0, stream>>>(C_s, C_t, s_out, t_out,
                                                  offs_fwd, offs_bwd, pay_fwd, pay_bwd,
                                                  dsi, dti, noise_s, noise_t, N_NODES);
}